// Round 2
// baseline (1355.397 us; speedup 1.0000x reference)
//
#include <hip/hip_runtime.h>
#include <hip/hip_bf16.h>

// QLinear int4-dequant GEMM: C[8192,11008] = X[8192,4096](fp32) @ deq(W)[4096,11008]
// deq: w[k][n] = (nibble(pack[k>>3][n], k&7) - zp[n]) * sc[n], nibble j at bits [28-4j : 31-4j]
// Fused m93-style bf16 MFMA kernel: 128x128 tile, BK=32, 256 thr (4 waves, 2x2),
// per-wave 4x4 tiles of mfma_f32_16x16x32_bf16. Register-prefetch staging.

#define K_DIM 4096
#define N_DIM 11008
#define M_DIM 8192
#define LDA 40  // LDS row stride (elements): 32 + 8 pad -> 80 B rows (16B-aligned), ~2-way banks

typedef __attribute__((ext_vector_type(8))) short short8;      // 8 x bf16 (4 VGPRs) MFMA A/B frag
typedef __attribute__((ext_vector_type(4))) float f32x4;       // MFMA C/D frag / float4 loads
typedef __attribute__((ext_vector_type(4))) unsigned int u32x4; // 16B LDS store of 8 bf16

__global__ __launch_bounds__(256, 3) void qgemm_fused(
    const float* __restrict__ X, const int* __restrict__ Q,
    const float* __restrict__ SC, const float* __restrict__ ZP,
    float* __restrict__ C)
{
    __shared__ short As[128 * LDA];
    __shared__ short Bs[128 * LDA];

    const int tid  = threadIdx.x;
    const int lane = tid & 63;
    const int wave = tid >> 6;

    const int m0 = blockIdx.y * 128;
    const int n0 = blockIdx.x * 128;

    // ---- A staging map: (row, k8) = (tid>>2 [+64], (tid&3)*8), 8 floats each pass
    const int arow = tid >> 2;
    const int ak8  = (tid & 3) * 8;
    const float* xbase = X + (size_t)(m0 + arow) * K_DIM + ak8;

    // ---- B staging map: col = tid&127 (fixed all K!), word rows brow0 and brow0+2
    const int bcol  = tid & 127;
    const int brow0 = tid >> 7;
    const int* qbase = Q + (size_t)brow0 * N_DIM + n0 + bcol;
    const float sc  = SC[n0 + bcol];
    const float nzs = -ZP[n0 + bcol] * sc;   // exact affine: (float)nib * sc + nzs

    f32x4 areg[4];
    int   breg[2];

    auto load_tile = [&](int kt) {
        const float* p0 = xbase + kt;
        areg[0] = *(const f32x4*)(p0);
        areg[1] = *(const f32x4*)(p0 + 4);
        const float* p1 = p0 + (size_t)64 * K_DIM;
        areg[2] = *(const f32x4*)(p1);
        areg[3] = *(const f32x4*)(p1 + 4);
        const int* q0 = qbase + (size_t)(kt >> 3) * N_DIM;
        breg[0] = q0[0];
        breg[1] = q0[2 * N_DIM];
    };

    auto cvt2 = [&](float a, float b) -> unsigned {
        __hip_bfloat162 h = __float22bfloat162_rn(make_float2(a, b));
        unsigned u;
        __builtin_memcpy(&u, &h, 4);
        return u;
    };

    auto store_tile = [&]() {
        #pragma unroll
        for (int p = 0; p < 2; ++p) {
            u32x4 v;
            v[0] = cvt2(areg[2*p+0][0], areg[2*p+0][1]);
            v[1] = cvt2(areg[2*p+0][2], areg[2*p+0][3]);
            v[2] = cvt2(areg[2*p+1][0], areg[2*p+1][1]);
            v[3] = cvt2(areg[2*p+1][2], areg[2*p+1][3]);
            *(u32x4*)&As[(arow + p * 64) * LDA + ak8] = v;
        }
        #pragma unroll
        for (int r = 0; r < 2; ++r) {
            const unsigned w = (unsigned)breg[r];
            float f[8];
            #pragma unroll
            for (int j = 0; j < 8; ++j)   // k = kw*8 + j, nibble j at bits [28-4j..]
                f[j] = fmaf((float)((w >> (28 - 4*j)) & 15u), sc, nzs);
            u32x4 v;
            v[0] = cvt2(f[0], f[1]);
            v[1] = cvt2(f[2], f[3]);
            v[2] = cvt2(f[4], f[5]);
            v[3] = cvt2(f[6], f[7]);
            *(u32x4*)&Bs[bcol * LDA + (brow0 + 2*r) * 8] = v;  // Bs[n][k], k-contiguous
        }
    };

    f32x4 acc[4][4] = {};

    const int wm = (wave >> 1) * 64;   // wave 2x2 grid: rows
    const int wn = (wave & 1) * 64;    // cols
    const int fr = lane & 15;
    const int fq = lane >> 4;

    // A frag: A[m=lane&15][k=fq*8+j]; B frag: B[k=fq*8+j][n=lane&15] read from Bs[n][k]
    const short* Abase = &As[(wm + fr) * LDA + fq * 8];
    const short* Bbase = &Bs[(wn + fr) * LDA + fq * 8];

    load_tile(0);
    store_tile();
    __syncthreads();

    for (int kt = 0;;) {
        const int knext = kt + 32;
        const bool last = (knext >= K_DIM);
        if (!last) load_tile(knext);   // prefetch next tile into registers (overlaps MFMA)

        short8 af[4], bf[4];
        #pragma unroll
        for (int i = 0; i < 4; ++i) {
            af[i] = *(const short8*)(Abase + i * 16 * LDA);
            bf[i] = *(const short8*)(Bbase + i * 16 * LDA);
        }
        #pragma unroll
        for (int mi = 0; mi < 4; ++mi)
            #pragma unroll
            for (int ni = 0; ni < 4; ++ni)
                acc[mi][ni] = __builtin_amdgcn_mfma_f32_16x16x32_bf16(
                    af[mi], bf[ni], acc[mi][ni], 0, 0, 0);

        if (last) break;
        __syncthreads();
        store_tile();
        __syncthreads();
        kt = knext;
    }

    // Epilogue: C/D layout col=lane&15, row=fq*4+r (m89/m91-verified)
    #pragma unroll
    for (int mi = 0; mi < 4; ++mi) {
        #pragma unroll
        for (int ni = 0; ni < 4; ++ni) {
            const int row = m0 + wm + mi * 16 + fq * 4;
            const int col = n0 + wn + ni * 16 + fr;
            float* cp = C + (size_t)row * N_DIM + col;
            #pragma unroll
            for (int r = 0; r < 4; ++r)
                cp[(size_t)r * N_DIM] = acc[mi][ni][r];
        }
    }
}

extern "C" void kernel_launch(void* const* d_in, const int* in_sizes, int n_in,
                              void* d_out, int out_size, void* d_ws, size_t ws_size,
                              hipStream_t stream) {
    const float* X  = (const float*)d_in[0];
    const int*   Q  = (const int*)d_in[1];
    const float* SC = (const float*)d_in[2];
    const float* ZP = (const float*)d_in[3];
    float*       C  = (float*)d_out;
    (void)d_ws; (void)ws_size; (void)in_sizes; (void)n_in; (void)out_size;

    qgemm_fused<<<dim3(N_DIM / 128, M_DIM / 128), 256, 0, stream>>>(X, Q, SC, ZP, C);
}